// Round 1
// baseline (163.506 us; speedup 1.0000x reference)
//
#include <hip/hip_runtime.h>

// LTAE2d tiny: GN(16 groups over C=128,L=30 per pixel) -> 1x1 conv(256) -> +PE
// -> key proj -> learned-query scores -> softmax over L.
// Folded: score[h,pix,l] = 0.5*( sum_g inv_g*(d[h][g][l] - mu_g*U[h][g])
//                                + wb[h] + s0[h] + pterm[h][b][l] )
// with u[h][c] = (Q[h]·Wk_h)·conv_w · gn_w[c], all precomputed on-device.

#define SZB  4
#define LLEN 30
#define INC  128
#define NH   16
#define HW   4096       // 64*64
#define NPIX 16384      // SZB*HW
#define EPSV 1e-5f

// ws float offsets
#define WS_U    0          // u[c][h]        128*16 = 2048
#define WS_UU   2048       // U[g][h]        16*16  = 256
#define WS_P2   2304       // P2[b*30+l][h]  120*16 = 1920
#define WS_FLAG 4224       // flag[b*30+l]   120
#define WS_QT   4352       // qt[h][m]       16*256 = 4096
#define WS_WT   8448       // wt[h][c]       16*128 = 2048
#define WS_INV  10496      // inv[g][pix]    16*16384
#define WS_MUI  272640     // mu*inv[g][pix] 16*16384
// total = 534784 floats = 2.14 MB

// ---- k0a: qt[h][m] = sum_d Q[h][d]*Wk[h*4+d][m] ----
__global__ void k0a(const float* __restrict__ Q, const float* __restrict__ Wk,
                    float* __restrict__ ws) {
    int h = blockIdx.x, m = threadIdx.x;
    float s = 0.f;
    #pragma unroll
    for (int d = 0; d < 4; ++d) s += Q[h*4+d] * Wk[(h*4+d)*256 + m];
    ws[WS_QT + h*256 + m] = s;
}

// ---- k0b: wt[h][c] = qt[h]·conv_w[:,c];  u[c][h] = wt*gn_w[c] ----
__global__ void k0b(const float* __restrict__ conv_w, const float* __restrict__ gn_w,
                    float* __restrict__ ws) {
    int idx = blockIdx.x*256 + threadIdx.x;   // 8 blocks -> 2048 tasks
    int h = idx >> 7, c = idx & 127;
    const float* qt = ws + WS_QT + h*256;
    float s = 0.f;
    #pragma unroll 8
    for (int m = 0; m < 256; ++m) s += qt[m] * conv_w[m*128 + c];
    ws[WS_WT + h*128 + c] = s;
    ws[WS_U  + c*16  + h] = s * gn_w[c];
}

// ---- k0c: U[g][h], wb+s0 -> sc, qs, P2[b,l][h] = pterm + wb + s0, mask flags ----
__global__ void k0c(const float* __restrict__ Q, const float* __restrict__ conv_b,
                    const float* __restrict__ gn_b, const float* __restrict__ bk,
                    const int* __restrict__ bpos, const unsigned char* __restrict__ pmask,
                    float* __restrict__ ws) {
    __shared__ float sc[16];     // wb[h] + s0[h]
    __shared__ float qsv[256];   // qs[h][p] = sum_r qt[h][r*16+p]
    __shared__ float rden[16];   // 1/denom[p]
    int t = threadIdx.x;
    {   // U[g][h]
        int h = t >> 4, g = t & 15;
        float s = 0.f;
        #pragma unroll
        for (int cc = 0; cc < 8; ++cc) s += ws[WS_U + (g*8+cc)*16 + h];
        ws[WS_UU + g*16 + h] = s;
    }
    {   // qs
        int h = t >> 4, p = t & 15;
        float s = 0.f;
        #pragma unroll
        for (int r = 0; r < 16; ++r) s += ws[WS_QT + h*256 + r*16 + p];
        qsv[h*16 + p] = s;
    }
    if (t < 16) {
        int h = t;
        float wb = 0.f;
        for (int c = 0; c < 128; ++c) wb += ws[WS_WT + h*128 + c] * gn_b[c];
        float s0 = 0.f;
        for (int m = 0; m < 256; ++m) s0 += ws[WS_QT + h*256 + m] * conv_b[m];
        #pragma unroll
        for (int d = 0; d < 4; ++d) s0 += Q[h*4+d] * bk[h*4+d];
        sc[h] = wb + s0;
        rden[t] = powf(1000.0f, -((float)(t >> 1)) * 0.125f);  // 1000^{-(p//2)*2/16}
    }
    if (t < 120) ws[WS_FLAG + t] = pmask[t] ? 1.f : 0.f;
    __syncthreads();
    for (int idx = t; idx < 1920; idx += 256) {
        int h = idx / 120, r = idx % 120;       // r = b*30+l
        float pos = (float)bpos[r];
        float pt = 0.f;
        #pragma unroll
        for (int p = 0; p < 16; ++p) {
            float tab = pos * rden[p];
            float v = (p & 1) ? cosf(tab) : sinf(tab);
            pt += v * qsv[h*16 + p];
        }
        ws[WS_P2 + r*16 + h] = pt + sc[h];
    }
}

// ---- k1: per (pixel, group) mean & rsqrt(var+eps) over 8 channels x 30 l ----
__global__ void __launch_bounds__(256) k1(const float* __restrict__ x,
                                          float* __restrict__ ws) {
    int bx = blockIdx.x;               // 1024 blocks: g = bx>>6, pb = bx&63
    int g = bx >> 6, pb = bx & 63;
    int pix = pb*256 + threadIdx.x;
    int b = pix >> 12, pij = pix & 4095;
    const float* xp = x + (b*30*128 + g*8)*4096 + pij;
    float s = 0.f, ss = 0.f;
    for (int l = 0; l < 30; ++l) {
        const float* xl = xp + l*128*4096;
        #pragma unroll
        for (int c = 0; c < 8; ++c) {
            float v = xl[c*4096];
            s += v; ss += v*v;
        }
    }
    float mu  = s * (1.f/240.f);
    float var = ss * (1.f/240.f) - mu*mu;
    float inv = rsqrtf(var + EPSV);
    ws[WS_INV + g*16384 + pix] = inv;
    ws[WS_MUI + g*16384 + pix] = mu * inv;
}

// ---- k2: raw scores -> d_out[(h*4+b)*30+l][pij] ----
__global__ void __launch_bounds__(256) k2(const float* __restrict__ x,
                                          const float* __restrict__ ws,
                                          float* __restrict__ out) {
    __shared__ float su[2048];   // u[c][h]
    __shared__ float sU[256];    // U[g][h]
    __shared__ float sP2[16];
    __shared__ float sflag;
    int t = threadIdx.x;
    int bx = blockIdx.x;                 // 1920 blocks: pb-major so siblings share stats in L2
    int pb = bx / 30, l = bx % 30;
    int pix = pb*256 + t;
    int b = pix >> 12, pij = pix & 4095;
    int bl = b*30 + l;
    for (int i = t; i < 2048; i += 256) su[i] = ws[WS_U + i];
    sU[t] = ws[WS_UU + t];
    if (t < 16) sP2[t] = ws[WS_P2 + bl*16 + t];
    if (t == 0) sflag = ws[WS_FLAG + bl];
    __syncthreads();

    float acc[16];
    #pragma unroll
    for (int h = 0; h < 16; ++h) acc[h] = 0.f;
    const float* xbase = x + (bl*128)*4096 + pij;
    for (int g = 0; g < 16; ++g) {
        float inv = ws[WS_INV + g*16384 + pix];
        float mui = ws[WS_MUI + g*16384 + pix];
        const float* us = su + g*8*16;
        const float* Ug = sU + g*16;
        #pragma unroll
        for (int h = 0; h < 16; ++h) acc[h] -= mui * Ug[h];
        const float* xg = xbase + g*8*4096;
        #pragma unroll
        for (int cc = 0; cc < 8; ++cc) {
            float xs = xg[cc*4096] * inv;
            #pragma unroll
            for (int h = 0; h < 16; ++h) acc[h] += us[cc*16 + h] * xs;
        }
    }
    bool msk = (sflag != 0.f);
    #pragma unroll
    for (int h = 0; h < 16; ++h) {
        float sv = 0.5f * (acc[h] + sP2[h]);
        if (msk) sv = -1000.f;
        out[((h*4 + b)*30 + l)*4096 + pij] = sv;
    }
}

// ---- k3: softmax over l (30) in place on d_out ----
__global__ void __launch_bounds__(256) k3(float* __restrict__ out) {
    int idx = blockIdx.x*256 + threadIdx.x;   // 1024 blocks over 16*4*4096 columns
    int hb = idx >> 12, pij = idx & 4095;
    float* p = out + hb*30*4096 + pij;
    float v[30];
    float m = -1e30f;
    #pragma unroll
    for (int l = 0; l < 30; ++l) { v[l] = p[l*4096]; m = fmaxf(m, v[l]); }
    float s = 0.f;
    #pragma unroll
    for (int l = 0; l < 30; ++l) { v[l] = __expf(v[l] - m); s += v[l]; }
    float r = 1.f / s;
    #pragma unroll
    for (int l = 0; l < 30; ++l) p[l*4096] = v[l] * r;
}

extern "C" void kernel_launch(void* const* d_in, const int* in_sizes, int n_in,
                              void* d_out, int out_size, void* d_ws, size_t ws_size,
                              hipStream_t stream) {
    const float* x      = (const float*)d_in[0];
    const float* gn_w   = (const float*)d_in[1];
    const float* gn_b   = (const float*)d_in[2];
    const float* conv_w = (const float*)d_in[3];
    const float* conv_b = (const float*)d_in[4];
    const float* Q      = (const float*)d_in[5];
    const float* Wk     = (const float*)d_in[6];
    const float* bk     = (const float*)d_in[7];
    const int*   bpos   = (const int*)d_in[8];
    const unsigned char* pmask = (const unsigned char*)d_in[9];
    float* ws  = (float*)d_ws;
    float* out = (float*)d_out;

    hipLaunchKernelGGL(k0a, dim3(16),   dim3(256), 0, stream, Q, Wk, ws);
    hipLaunchKernelGGL(k0b, dim3(8),    dim3(256), 0, stream, conv_w, gn_w, ws);
    hipLaunchKernelGGL(k0c, dim3(1),    dim3(256), 0, stream, Q, conv_b, gn_b, bk, bpos, pmask, ws);
    hipLaunchKernelGGL(k1,  dim3(1024), dim3(256), 0, stream, x, ws);
    hipLaunchKernelGGL(k2,  dim3(1920), dim3(256), 0, stream, x, ws, out);
    hipLaunchKernelGGL(k3,  dim3(1024), dim3(256), 0, stream, out);
}

// Round 2
// 163.110 us; speedup vs baseline: 1.0024x; 1.0024x over previous
//
#include <hip/hip_runtime.h>

// LTAE2d tiny, folded: score[h,pix,l] = 0.5*( sum_g inv_g*(d_g[h][l] - mu_g*U[h][g])
//                                             + wb[h] + s0[h] + pterm[h][b][l] )
// u[h][c] = (Q[h]·Wk_h)·conv_w · gn_w[c] precomputed on-device (k0, single block).
// k1: per (pixel,group) GN stats. k2: scores. k3: softmax over L=30.

#define EPSV 1e-5f

// ws float offsets
#define WS_U    0          // u[c][h]        128*16
#define WS_UU   2048       // U[g][h]        16*16
#define WS_P2   2304       // P2[b*30+l][h]  120*16
#define WS_FLAG 4224       // flag[b*30+l]   120
#define WS_QT   4352       // qt[h][m]       16*256
#define WS_WT   8448       // wt[h][c]       16*128
#define WS_INV  10496      // inv[g][pix]    16*16384
#define WS_MUI  272640     // mu*inv[g][pix] 16*16384

// ---- k0: all small precompute, one block of 1024 ----
__global__ void __launch_bounds__(1024) k0(const float* __restrict__ Q,
                                           const float* __restrict__ Wk,
                                           const float* __restrict__ conv_w,
                                           const float* __restrict__ gn_w,
                                           const float* __restrict__ conv_b,
                                           const float* __restrict__ gn_b,
                                           const float* __restrict__ bk,
                                           const int* __restrict__ bpos,
                                           const unsigned char* __restrict__ pmask,
                                           float* __restrict__ ws) {
    int t = threadIdx.x;
    // stage A: qt[h][m] = sum_d Q[h][d]*Wk[h*4+d][m]
    for (int i = t; i < 4096; i += 1024) {
        int h = i >> 8, m = i & 255;
        float s = 0.f;
        #pragma unroll
        for (int d = 0; d < 4; ++d) s += Q[h*4+d] * Wk[(h*4+d)*256 + m];
        ws[WS_QT + h*256 + m] = s;
    }
    __syncthreads();
    // stage B: wt[h][c] = qt[h]·conv_w[:,c]; u[c][h] = wt*gn_w[c]
    for (int i = t; i < 2048; i += 1024) {
        int h = i >> 7, c = i & 127;
        const float* qt = ws + WS_QT + h*256;
        float s = 0.f;
        #pragma unroll 8
        for (int m = 0; m < 256; ++m) s += qt[m] * conv_w[m*128 + c];
        ws[WS_WT + h*128 + c] = s;
        ws[WS_U  + c*16  + h] = s * gn_w[c];
    }
    __syncthreads();
    // stage C
    __shared__ float sc[16];
    __shared__ float qsv[256];
    __shared__ float rden[16];
    if (t < 256) {
        int h = t >> 4, g = t & 15;
        float s = 0.f;
        #pragma unroll
        for (int cc = 0; cc < 8; ++cc) s += ws[WS_U + (g*8+cc)*16 + h];
        ws[WS_UU + g*16 + h] = s;
        float q = 0.f;
        #pragma unroll
        for (int r = 0; r < 16; ++r) q += ws[WS_QT + h*256 + r*16 + g];
        qsv[h*16 + g] = q;
    }
    if (t < 16) {
        int h = t;
        float wb = 0.f;
        for (int c = 0; c < 128; ++c) wb += ws[WS_WT + h*128 + c] * gn_b[c];
        float s0 = 0.f;
        for (int m = 0; m < 256; ++m) s0 += ws[WS_QT + h*256 + m] * conv_b[m];
        #pragma unroll
        for (int d = 0; d < 4; ++d) s0 += Q[h*4+d] * bk[h*4+d];
        sc[h] = wb + s0;
        rden[t] = powf(1000.0f, -((float)(t >> 1)) * 0.125f);
    }
    if (t < 120) ws[WS_FLAG + t] = pmask[t] ? 1.f : 0.f;
    __syncthreads();
    for (int idx = t; idx < 1920; idx += 1024) {
        int h = idx / 120, r = idx - h*120;     // r = b*30+l
        float pos = (float)bpos[r];
        float pt = 0.f;
        #pragma unroll
        for (int p = 0; p < 16; ++p) {
            float tab = pos * rden[p];
            float v = (p & 1) ? cosf(tab) : sinf(tab);
            pt += v * qsv[h*16 + p];
        }
        ws[WS_P2 + r*16 + h] = pt + sc[h];
    }
}

// ---- k1: GN stats, 2 pixels/thread, float2 loads ----
__global__ void __launch_bounds__(256) k1(const float* __restrict__ x,
                                          float* __restrict__ ws) {
    int bx = blockIdx.x;                     // 512 blocks: g = bx>>5
    int g = bx >> 5;
    int pq = (bx & 31)*256 + threadIdx.x;    // 0..8191
    int pix0 = pq*2;
    int b = pix0 >> 12, pij = pix0 & 4095;
    const float2* xp = (const float2*)(x + (b*30*128 + g*8)*4096 + pij);
    float sx = 0.f, sy = 0.f, ssx = 0.f, ssy = 0.f;
    for (int l = 0; l < 30; ++l) {
        const float2* xl = xp + l*128*2048;
        #pragma unroll
        for (int c = 0; c < 8; ++c) {
            float2 v = xl[c*2048];
            sx += v.x; sy += v.y;
            ssx += v.x*v.x; ssy += v.y*v.y;
        }
    }
    float mux = sx*(1.f/240.f), muy = sy*(1.f/240.f);
    float ivx = rsqrtf(ssx*(1.f/240.f) - mux*mux + EPSV);
    float ivy = rsqrtf(ssy*(1.f/240.f) - muy*muy + EPSV);
    *(float2*)(ws + WS_INV + g*16384 + pix0) = make_float2(ivx, ivy);
    *(float2*)(ws + WS_MUI + g*16384 + pix0) = make_float2(mux*ivx, muy*ivy);
}

// ---- k2: raw scores, 2 pixels/thread ----
__global__ void __launch_bounds__(256) k2(const float* __restrict__ x,
                                          const float* __restrict__ ws,
                                          float* __restrict__ out) {
    __shared__ float su[2048];
    __shared__ float sU[256];
    __shared__ float sP2[16];
    __shared__ float sflag;
    int t = threadIdx.x;
    int bx = blockIdx.x;                 // 960 blocks: pb2 = bx/30, l = bx%30
    int pb2 = bx / 30, l = bx - pb2*30;
    int pix0 = (pb2*256 + t)*2;
    int b = pix0 >> 12, pij = pix0 & 4095;
    int bl = b*30 + l;
    for (int i = t; i < 2048; i += 256) su[i] = ws[WS_U + i];
    sU[t] = ws[WS_UU + t];
    if (t < 16) sP2[t] = ws[WS_P2 + bl*16 + t];
    if (t == 0) sflag = ws[WS_FLAG + bl];
    __syncthreads();

    float a0[16], a1[16];
    #pragma unroll
    for (int h = 0; h < 16; ++h) { a0[h] = 0.f; a1[h] = 0.f; }
    const float* xbase = x + (bl*128)*4096 + pij;
    for (int g = 0; g < 16; ++g) {
        float2 inv = *(const float2*)(ws + WS_INV + g*16384 + pix0);
        float2 mui = *(const float2*)(ws + WS_MUI + g*16384 + pix0);
        const float* us = su + g*128;
        const float* Ug = sU + g*16;
        #pragma unroll
        for (int h = 0; h < 16; ++h) { a0[h] -= mui.x*Ug[h]; a1[h] -= mui.y*Ug[h]; }
        const float* xg = xbase + g*8*4096;
        #pragma unroll
        for (int cc = 0; cc < 8; ++cc) {
            float2 v = *(const float2*)(xg + cc*4096);
            float xs0 = v.x*inv.x, xs1 = v.y*inv.y;
            #pragma unroll
            for (int h = 0; h < 16; ++h) {
                float uu = us[cc*16 + h];
                a0[h] += uu*xs0; a1[h] += uu*xs1;
            }
        }
    }
    bool msk = (sflag != 0.f);
    #pragma unroll
    for (int h = 0; h < 16; ++h) {
        float s0 = 0.5f*(a0[h] + sP2[h]);
        float s1 = 0.5f*(a1[h] + sP2[h]);
        if (msk) { s0 = -1000.f; s1 = -1000.f; }
        *(float2*)(out + ((h*4 + b)*30 + l)*4096 + pij) = make_float2(s0, s1);
    }
}

// ---- k3: softmax over l, 2 pixels/thread ----
__global__ void __launch_bounds__(256) k3(float* __restrict__ out) {
    int idx = blockIdx.x*256 + threadIdx.x;   // 512 blocks, 131072 threads
    int hb = idx >> 11;                       // 64 (h*4+b) slabs
    int pij = (idx & 2047)*2;
    float* p = out + hb*30*4096 + pij;
    float2 v[30];
    float m0 = -1e30f, m1 = -1e30f;
    #pragma unroll
    for (int l = 0; l < 30; ++l) {
        v[l] = *(const float2*)(p + l*4096);
        m0 = fmaxf(m0, v[l].x); m1 = fmaxf(m1, v[l].y);
    }
    float s0 = 0.f, s1 = 0.f;
    #pragma unroll
    for (int l = 0; l < 30; ++l) {
        v[l].x = __expf(v[l].x - m0); s0 += v[l].x;
        v[l].y = __expf(v[l].y - m1); s1 += v[l].y;
    }
    float r0 = 1.f/s0, r1 = 1.f/s1;
    #pragma unroll
    for (int l = 0; l < 30; ++l) {
        *(float2*)(p + l*4096) = make_float2(v[l].x*r0, v[l].y*r1);
    }
}

extern "C" void kernel_launch(void* const* d_in, const int* in_sizes, int n_in,
                              void* d_out, int out_size, void* d_ws, size_t ws_size,
                              hipStream_t stream) {
    const float* x      = (const float*)d_in[0];
    const float* gn_w   = (const float*)d_in[1];
    const float* gn_b   = (const float*)d_in[2];
    const float* conv_w = (const float*)d_in[3];
    const float* conv_b = (const float*)d_in[4];
    const float* Q      = (const float*)d_in[5];
    const float* Wk     = (const float*)d_in[6];
    const float* bk     = (const float*)d_in[7];
    const int*   bpos   = (const int*)d_in[8];
    const unsigned char* pmask = (const unsigned char*)d_in[9];
    float* ws  = (float*)d_ws;
    float* out = (float*)d_out;

    hipLaunchKernelGGL(k0, dim3(1),    dim3(1024), 0, stream,
                       Q, Wk, conv_w, gn_w, conv_b, gn_b, bk, bpos, pmask, ws);
    hipLaunchKernelGGL(k1, dim3(512),  dim3(256),  0, stream, x, ws);
    hipLaunchKernelGGL(k2, dim3(960),  dim3(256),  0, stream, x, ws, out);
    hipLaunchKernelGGL(k3, dim3(512),  dim3(256),  0, stream, out);
}

// Round 3
// 156.021 us; speedup vs baseline: 1.0480x; 1.0454x over previous
//
#include <hip/hip_runtime.h>

// LTAE2d tiny, folded: score[h,pix,l] = 0.5*( sum_g inv_g*(d_g[h][l] - mu_g*U[h][g])
//                                             + wb[h] + s0[h] + pterm[h][b][l] )
// u[h][c] = (Q[h]·Wk_h)·conv_w · gn_w[c] precomputed on-device (k0, single block).
// k1: per (pixel,group) GN stats. k2: scores (float4 px, b128 u-reads). k3: softmax.

#define EPSV 1e-5f

// ws float offsets
#define WS_U    0          // u[c][h]        128*16
#define WS_UU   2048       // U[g][h]        16*16
#define WS_P2   2304       // P2[b*30+l][h]  120*16
#define WS_FLAG 4224       // flag[b*30+l]   120
#define WS_QT   4352       // qt[h][m]       16*256
#define WS_WT   8448       // wt[h][c]       16*128
#define WS_INV  10496      // inv[g][pix]    16*16384
#define WS_MUI  272640     // mu*inv[g][pix] 16*16384

// ---- k0: all small precompute, one block of 1024 ----
__global__ void __launch_bounds__(1024) k0(const float* __restrict__ Q,
                                           const float* __restrict__ Wk,
                                           const float* __restrict__ conv_w,
                                           const float* __restrict__ gn_w,
                                           const float* __restrict__ conv_b,
                                           const float* __restrict__ gn_b,
                                           const float* __restrict__ bk,
                                           const int* __restrict__ bpos,
                                           const unsigned char* __restrict__ pmask,
                                           float* __restrict__ ws) {
    int t = threadIdx.x;
    for (int i = t; i < 4096; i += 1024) {
        int h = i >> 8, m = i & 255;
        float s = 0.f;
        #pragma unroll
        for (int d = 0; d < 4; ++d) s += Q[h*4+d] * Wk[(h*4+d)*256 + m];
        ws[WS_QT + h*256 + m] = s;
    }
    __syncthreads();
    for (int i = t; i < 2048; i += 1024) {
        int h = i >> 7, c = i & 127;
        const float* qt = ws + WS_QT + h*256;
        float s = 0.f;
        #pragma unroll 8
        for (int m = 0; m < 256; ++m) s += qt[m] * conv_w[m*128 + c];
        ws[WS_WT + h*128 + c] = s;
        ws[WS_U  + c*16  + h] = s * gn_w[c];
    }
    __syncthreads();
    __shared__ float sc[16];
    __shared__ float qsv[256];
    __shared__ float rden[16];
    if (t < 256) {
        int h = t >> 4, g = t & 15;
        float s = 0.f;
        #pragma unroll
        for (int cc = 0; cc < 8; ++cc) s += ws[WS_U + (g*8+cc)*16 + h];
        ws[WS_UU + g*16 + h] = s;
        float q = 0.f;
        #pragma unroll
        for (int r = 0; r < 16; ++r) q += ws[WS_QT + h*256 + r*16 + g];
        qsv[h*16 + g] = q;
    }
    if (t < 16) {
        int h = t;
        float wb = 0.f;
        for (int c = 0; c < 128; ++c) wb += ws[WS_WT + h*128 + c] * gn_b[c];
        float s0 = 0.f;
        for (int m = 0; m < 256; ++m) s0 += ws[WS_QT + h*256 + m] * conv_b[m];
        #pragma unroll
        for (int d = 0; d < 4; ++d) s0 += Q[h*4+d] * bk[h*4+d];
        sc[h] = wb + s0;
        rden[t] = powf(1000.0f, -((float)(t >> 1)) * 0.125f);
    }
    if (t < 120) ws[WS_FLAG + t] = pmask[t] ? 1.f : 0.f;
    __syncthreads();
    for (int idx = t; idx < 1920; idx += 1024) {
        int h = idx / 120, r = idx - h*120;     // r = b*30+l
        float pos = (float)bpos[r];
        float pt = 0.f;
        #pragma unroll
        for (int p = 0; p < 16; ++p) {
            float tab = pos * rden[p];
            float v = (p & 1) ? cosf(tab) : sinf(tab);
            pt += v * qsv[h*16 + p];
        }
        ws[WS_P2 + r*16 + h] = pt + sc[h];
    }
}

// ---- k1: GN stats, 2 pixels/thread, float2 loads ----
__global__ void __launch_bounds__(256) k1(const float* __restrict__ x,
                                          float* __restrict__ ws) {
    int bx = blockIdx.x;                     // 512 blocks: g = bx>>5
    int g = bx >> 5;
    int pq = (bx & 31)*256 + threadIdx.x;
    int pix0 = pq*2;
    int b = pix0 >> 12, pij = pix0 & 4095;
    const float2* xp = (const float2*)(x + (b*30*128 + g*8)*4096 + pij);
    float sx = 0.f, sy = 0.f, ssx = 0.f, ssy = 0.f;
    for (int l = 0; l < 30; ++l) {
        const float2* xl = xp + l*128*2048;
        #pragma unroll
        for (int c = 0; c < 8; ++c) {
            float2 v = xl[c*2048];
            sx += v.x; sy += v.y;
            ssx += v.x*v.x; ssy += v.y*v.y;
        }
    }
    float mux = sx*(1.f/240.f), muy = sy*(1.f/240.f);
    float ivx = rsqrtf(ssx*(1.f/240.f) - mux*mux + EPSV);
    float ivy = rsqrtf(ssy*(1.f/240.f) - muy*muy + EPSV);
    *(float2*)(ws + WS_INV + g*16384 + pix0) = make_float2(ivx, ivy);
    *(float2*)(ws + WS_MUI + g*16384 + pix0) = make_float2(mux*ivx, muy*ivy);
}

#define FMA4(A, S, V) { (A).x += (S)*(V).x; (A).y += (S)*(V).y; (A).z += (S)*(V).z; (A).w += (S)*(V).w; }
#define NMA4(A, S, V) { (A).x -= (S)*(V).x; (A).y -= (S)*(V).y; (A).z -= (S)*(V).z; (A).w -= (S)*(V).w; }

// ---- k2: raw scores, 4 pixels/thread, float4 everywhere, b128 u-reads ----
__global__ void __launch_bounds__(256) k2(const float* __restrict__ x,
                                          const float* __restrict__ ws,
                                          float* __restrict__ out) {
    __shared__ float su[2048];   // u[c][h], h contiguous
    __shared__ float sU[256];    // U[g][h], h contiguous
    __shared__ float sP2[16];
    __shared__ float sflag;
    int t = threadIdx.x;
    int bx = blockIdx.x;                 // 480 blocks: pb2 = bx/30, l = bx%30
    int pb2 = bx / 30, l = bx - pb2*30;
    int pixbase = pb2 * 1024;            // block-uniform
    int b = pixbase >> 12;               // block-uniform (1024 | 4096)
    int pijb = pixbase & 4095;           // block-uniform
    int bl = b*30 + l;                   // block-uniform
    int pij = pijb + t*4;
    int pix0 = pixbase + t*4;

    for (int i = t; i < 512; i += 256)
        *(float4*)(su + i*4) = *(const float4*)(ws + WS_U + i*4);
    sU[t] = ws[WS_UU + t];
    if (t < 16) sP2[t] = ws[WS_P2 + bl*16 + t];
    if (t == 0) sflag = ws[WS_FLAG + bl];
    __syncthreads();

    float4 acc[16];
    #pragma unroll
    for (int h = 0; h < 16; ++h) acc[h] = make_float4(0.f, 0.f, 0.f, 0.f);
    const float* xbase = x + (bl*128)*4096 + pij;
    #pragma unroll 1
    for (int g = 0; g < 16; ++g) {
        float4 inv = *(const float4*)(ws + WS_INV + g*16384 + pix0);
        float4 mui = *(const float4*)(ws + WS_MUI + g*16384 + pix0);
        const float* us = su + g*128;
        #pragma unroll
        for (int q = 0; q < 4; ++q) {
            float4 Ug = *(const float4*)(sU + g*16 + q*4);
            NMA4(acc[q*4+0], Ug.x, mui); NMA4(acc[q*4+1], Ug.y, mui);
            NMA4(acc[q*4+2], Ug.z, mui); NMA4(acc[q*4+3], Ug.w, mui);
        }
        const float* xg = xbase + g*8*4096;
        #pragma unroll
        for (int cc = 0; cc < 8; ++cc) {
            float4 v = *(const float4*)(xg + cc*4096);
            float4 xs;
            xs.x = v.x*inv.x; xs.y = v.y*inv.y; xs.z = v.z*inv.z; xs.w = v.w*inv.w;
            #pragma unroll
            for (int q = 0; q < 4; ++q) {
                float4 uq = *(const float4*)(us + cc*16 + q*4);  // ds_read_b128 broadcast
                FMA4(acc[q*4+0], uq.x, xs); FMA4(acc[q*4+1], uq.y, xs);
                FMA4(acc[q*4+2], uq.z, xs); FMA4(acc[q*4+3], uq.w, xs);
            }
        }
    }
    bool msk = (sflag != 0.f);
    #pragma unroll
    for (int h = 0; h < 16; ++h) {
        float p2 = sP2[h];
        float4 sv;
        sv.x = 0.5f*(acc[h].x + p2); sv.y = 0.5f*(acc[h].y + p2);
        sv.z = 0.5f*(acc[h].z + p2); sv.w = 0.5f*(acc[h].w + p2);
        if (msk) sv = make_float4(-1000.f, -1000.f, -1000.f, -1000.f);
        *(float4*)(out + ((h*4 + b)*30 + l)*4096 + pij) = sv;
    }
}

// ---- k3: softmax over l, 4 pixels/thread ----
__global__ void __launch_bounds__(256) k3(float* __restrict__ out) {
    int idx = blockIdx.x*256 + threadIdx.x;   // 256 blocks, 65536 threads
    int hb = idx >> 10;                       // 64 (h*4+b) slabs
    int pij = (idx & 1023)*4;
    float* p = out + hb*30*4096 + pij;
    float4 v[30];
    float4 m = make_float4(-1e30f, -1e30f, -1e30f, -1e30f);
    #pragma unroll
    for (int l = 0; l < 30; ++l) {
        v[l] = *(const float4*)(p + l*4096);
        m.x = fmaxf(m.x, v[l].x); m.y = fmaxf(m.y, v[l].y);
        m.z = fmaxf(m.z, v[l].z); m.w = fmaxf(m.w, v[l].w);
    }
    float4 s = make_float4(0.f, 0.f, 0.f, 0.f);
    #pragma unroll
    for (int l = 0; l < 30; ++l) {
        v[l].x = __expf(v[l].x - m.x); s.x += v[l].x;
        v[l].y = __expf(v[l].y - m.y); s.y += v[l].y;
        v[l].z = __expf(v[l].z - m.z); s.z += v[l].z;
        v[l].w = __expf(v[l].w - m.w); s.w += v[l].w;
    }
    float4 r; r.x = 1.f/s.x; r.y = 1.f/s.y; r.z = 1.f/s.z; r.w = 1.f/s.w;
    #pragma unroll
    for (int l = 0; l < 30; ++l) {
        float4 o;
        o.x = v[l].x*r.x; o.y = v[l].y*r.y; o.z = v[l].z*r.z; o.w = v[l].w*r.w;
        *(float4*)(p + l*4096) = o;
    }
}

extern "C" void kernel_launch(void* const* d_in, const int* in_sizes, int n_in,
                              void* d_out, int out_size, void* d_ws, size_t ws_size,
                              hipStream_t stream) {
    const float* x      = (const float*)d_in[0];
    const float* gn_w   = (const float*)d_in[1];
    const float* gn_b   = (const float*)d_in[2];
    const float* conv_w = (const float*)d_in[3];
    const float* conv_b = (const float*)d_in[4];
    const float* Q      = (const float*)d_in[5];
    const float* Wk     = (const float*)d_in[6];
    const float* bk     = (const float*)d_in[7];
    const int*   bpos   = (const int*)d_in[8];
    const unsigned char* pmask = (const unsigned char*)d_in[9];
    float* ws  = (float*)d_ws;
    float* out = (float*)d_out;

    hipLaunchKernelGGL(k0, dim3(1),   dim3(1024), 0, stream,
                       Q, Wk, conv_w, gn_w, conv_b, gn_b, bk, bpos, pmask, ws);
    hipLaunchKernelGGL(k1, dim3(512), dim3(256),  0, stream, x, ws);
    hipLaunchKernelGGL(k2, dim3(480), dim3(256),  0, stream, x, ws, out);
    hipLaunchKernelGGL(k3, dim3(256), dim3(256),  0, stream, out);
}